// Round 19
// baseline (173.574 us; speedup 1.0000x reference)
//
#include <hip/hip_runtime.h>

#define SN (8192 * 64)

typedef unsigned short u16;
typedef unsigned int   u32;
typedef unsigned long long u64;
typedef __bf16 bf16x8 __attribute__((ext_vector_type(8)));
typedef float  f32x4  __attribute__((ext_vector_type(4)));

__device__ __forceinline__ u16 bfc(float x) {
  union { __bf16 b; u16 u; } v; v.b = (__bf16)x; return v.u;
}
__device__ __forceinline__ u64 pack4(float a, float b, float c, float d) {
  return (u64)bfc(a) | ((u64)bfc(b) << 16) | ((u64)bfc(c) << 32) | ((u64)bfc(d) << 48);
}
__device__ __forceinline__ float ftanh(float x) {
  float e = __expf(2.f * x);
  return 1.f - 2.f / (e + 1.f);
}

// ---------------- merged prep kernel ----------------
__device__ __forceinline__ void pack_body(
    const float* __restrict__ W, u16* __restrict__ P, int ksl, int N, int gid) {
  int lane = gid & 63, fid = gid >> 6;
  int ks = fid & ((1 << ksl) - 1);
  int nt = fid >> ksl;
  int n  = nt * 16 + (lane & 15);
  int k0 = ks * 32 + (lane >> 4) * 8;
  u64 lo = pack4(W[(size_t)k0 * N + n], W[(size_t)(k0 + 1) * N + n],
                 W[(size_t)(k0 + 2) * N + n], W[(size_t)(k0 + 3) * N + n]);
  u64 hi = pack4(W[(size_t)(k0 + 4) * N + n], W[(size_t)(k0 + 5) * N + n],
                 W[(size_t)(k0 + 6) * N + n], W[(size_t)(k0 + 7) * N + n]);
  u64* dst = (u64*)(P + (size_t)gid * 8);
  dst[0] = lo; dst[1] = hi;
}

// grid 580: [0,512) P2 ; [512,544) P1 ; [544,576) P3 ; [576,580) base1
__global__ __launch_bounds__(256) void k_prep(
    const float* __restrict__ W1, const float* __restrict__ b1,
    const float* __restrict__ ctx, float* __restrict__ base1,
    const float* __restrict__ W2, const float* __restrict__ W3,
    u16* __restrict__ P1, u16* __restrict__ P2, u16* __restrict__ P3) {
  int bid = blockIdx.x, tid = threadIdx.x;
  if (bid < 512) {
    pack_body(W2, P2, 5, 1024, bid * 256 + tid);
  } else if (bid < 544) {
    pack_body(W1, P1, 1, 1024, (bid - 512) * 256 + tid);
  } else if (bid < 576) {
    pack_body(W3, P3, 5, 64, (bid - 544) * 256 + tid);
  } else {
    int j = (bid - 576) * 256 + tid;
    float s = b1[j];
    for (int c = 0; c < 256; ++c)
      s += ctx[c] * W1[(size_t)(65 + c) * 1024 + j];
    base1[j] = s;
  }
}

// ---------------- k_l1: RK3-stage update + layer1 -> h1P ----------------
// Single Kutta RK3 step, h=1:
//   mode 0: x = theta0
//   mode 1: k1 = sum(kpart)+b3 ; K1 = k1 ; x = theta0 + 0.5*k1
//   mode 2: k2 = sum(kpart)+b3 ; K2 = k2 ; x = theta0 - K1 + 2*k2
__global__ __launch_bounds__(512, 4) void k_l1(
    const float* __restrict__ theta0, const float* __restrict__ kpart,
    const float* __restrict__ b3, float* __restrict__ K1,
    float* __restrict__ K2, const float* __restrict__ base1,
    const float* __restrict__ w1t, const u16* __restrict__ P1,
    u16* __restrict__ h1P, float t_s, int mode) {
  __shared__ u16 xs[32 * 64];          // 4 KB, 128B rows, slot ^= row&7
  __shared__ float bias[1024];         // 4 KB
  const int tid = threadIdx.x, wid = tid >> 6, lane = tid & 63;
  const int lrow = lane & 15, lk4 = lane >> 4;
  const int brow = blockIdx.x * 32;

  bias[tid]       = base1[tid]       + t_s * w1t[tid];
  bias[tid + 512] = base1[tid + 512] + t_s * w1t[tid + 512];

  {
    int row = tid >> 4, d = (tid & 15) * 4;
    int gi = (brow + row) * 64 + d;
    f32x4 x;
    if (mode == 0) {
      x = *(const f32x4*)(theta0 + gi);
    } else {
      f32x4 kv = *(const f32x4*)(kpart + gi);
      f32x4 p1 = *(const f32x4*)(kpart + SN + gi);
      f32x4 p2 = *(const f32x4*)(kpart + 2 * SN + gi);
      f32x4 p3 = *(const f32x4*)(kpart + 3 * SN + gi);
      f32x4 bv = *(const f32x4*)(b3 + d);
      f32x4 t0 = *(const f32x4*)(theta0 + gi);
#pragma unroll
      for (int j = 0; j < 4; ++j) kv[j] += p1[j] + p2[j] + p3[j] + bv[j];
      if (mode == 1) {
        *(f32x4*)(K1 + gi) = kv;
#pragma unroll
        for (int j = 0; j < 4; ++j) x[j] = t0[j] + 0.5f * kv[j];
      } else {
        f32x4 k1v = *(const f32x4*)(K1 + gi);
        *(f32x4*)(K2 + gi) = kv;
#pragma unroll
        for (int j = 0; j < 4; ++j) x[j] = t0[j] - k1v[j] + 2.f * kv[j];
      }
    }
    int slot = d >> 3, half = (d >> 2) & 1;
    *(u64*)((char*)xs + row * 128 + ((slot ^ (row & 7)) << 4) + half * 8)
        = pack4(x[0], x[1], x[2], x[3]);
  }
  __syncthreads();

#pragma unroll 1
  for (int nt = 0; nt < 8; ++nt) {
    const int n0 = wid * 128 + nt * 16;
    f32x4 acc[2] = {{0.f,0.f,0.f,0.f},{0.f,0.f,0.f,0.f}};
#pragma unroll
    for (int ks = 0; ks < 2; ++ks) {
      bf16x8 pw = *(const bf16x8*)(P1 + ((size_t)((n0 >> 4) * 2 + ks) << 9) + lane * 8);
#pragma unroll
      for (int st = 0; st < 2; ++st) {
        int row = st * 16 + lrow;
        bf16x8 xa = *(const bf16x8*)((char*)xs + row * 128 +
                                     (((ks * 4 + lk4) ^ (row & 7)) << 4));
        acc[st] = __builtin_amdgcn_mfma_f32_16x16x32_bf16(pw, xa, acc[st], 0, 0, 0);
      }
    }
    float bb0 = bias[n0 + lk4 * 4], bb1 = bias[n0 + lk4 * 4 + 1];
    float bb2 = bias[n0 + lk4 * 4 + 2], bb3 = bias[n0 + lk4 * 4 + 3];
    const int ks2 = n0 >> 5;
    const int lane2 = lrow + 16 * ((nt & 1) * 2 + (lk4 >> 1));
    const size_t off = (size_t)lane2 * 8 + (lk4 & 1) * 4;   // u16 units
#pragma unroll
    for (int st = 0; st < 2; ++st) {
      u64 pk = pack4(ftanh(acc[st][0] + bb0), ftanh(acc[st][1] + bb1),
                     ftanh(acc[st][2] + bb2), ftanh(acc[st][3] + bb3));
      *(u64*)(h1P + ((((size_t)(brow >> 4) + st) * 32 + ks2) << 9) + off) = pk;
    }
  }
}

// ---------------- k_fwd: layer2 + tanh + layer3-partial ----------------
// Tile 32 samples x 256 cols (grid 256 x 4 = 1024 blocks), 256 thr.
// __launch_bounds__(256,4): 4 blocks/CU resident -> 1024 slots == grid,
// ZERO scheduling tail (was 3/CU = 768 slots -> 256-block tail at 1/3 util).
// BARRIER-FREE K-loop, register-streamed A/B, setprio around MFMA (T5).
__global__ __launch_bounds__(256, 4) void k_fwd(
    const u16* __restrict__ h1P, const u16* __restrict__ P2,
    const float* __restrict__ b2, const u16* __restrict__ P3,
    float* __restrict__ kpart) {
  __shared__ u16 h2L[32 * 256];      // 16 KB
  __shared__ float b2l[256];         // 1 KB
  const int tid = threadIdx.x, wid = tid >> 6, lane = tid & 63;
  const int lrow = lane & 15, lk4 = lane >> 4;
  const int brow = blockIdx.x * 32, bcol = blockIdx.y * 256;
  const int wn = wid;                 // wave col-block (4 x 64 cols)

  b2l[tid] = b2[bcol + tid];
  __syncthreads();                    // b2l visible (only barrier pre-loop)

  const u16* Ph = h1P + (((size_t)(brow >> 4) * 32) << 9) + lane * 8;
  const u16* Pw = P2 + (((size_t)((bcol >> 4) + wn * 4) * 32) << 9) + lane * 8;

  bf16x8 AfE[2][2], AfO[2][2], BfE[2][4], BfO[2][4];
#define LOADAB(A, B, ks)                                                      \
  {                                                                           \
    _Pragma("unroll")                                                         \
    for (int n = 0; n < 4; ++n) {                                             \
      B[0][n] = *(const bf16x8*)(Pw + (((size_t)(n * 32 + (ks))) << 9));      \
      B[1][n] = *(const bf16x8*)(Pw + (((size_t)(n * 32 + (ks) + 1)) << 9));  \
    }                                                                         \
    _Pragma("unroll")                                                         \
    for (int m = 0; m < 2; ++m) {                                             \
      A[0][m] = *(const bf16x8*)(Ph + (((size_t)(m * 32 + (ks))) << 9));      \
      A[1][m] = *(const bf16x8*)(Ph + (((size_t)(m * 32 + (ks) + 1)) << 9));  \
    }                                                                         \
  }

  LOADAB(AfE, BfE, 0);

  f32x4 acc[4][2] = {};

#define ITER(T, AC, BC, AN, BN)                                               \
  {                                                                           \
    if ((T) < 15) LOADAB(AN, BN, 2 * (T) + 2);                                \
    __builtin_amdgcn_s_setprio(1);                                            \
    _Pragma("unroll")                                                         \
    for (int n = 0; n < 4; ++n)                                               \
      _Pragma("unroll")                                                       \
      for (int m = 0; m < 2; ++m)                                             \
        acc[n][m] = __builtin_amdgcn_mfma_f32_16x16x32_bf16(BC[0][n], AC[0][m],\
                                                            acc[n][m], 0, 0, 0);\
    _Pragma("unroll")                                                         \
    for (int n = 0; n < 4; ++n)                                               \
      _Pragma("unroll")                                                       \
      for (int m = 0; m < 2; ++m)                                             \
        acc[n][m] = __builtin_amdgcn_mfma_f32_16x16x32_bf16(BC[1][n], AC[1][m],\
                                                            acc[n][m], 0, 0, 0);\
    __builtin_amdgcn_s_setprio(0);                                            \
  }

#pragma unroll 1
  for (int tt = 0; tt < 8; ++tt) {
    ITER(2 * tt,     AfE, BfE, AfO, BfO);
    ITER(2 * tt + 1, AfO, BfO, AfE, BfE);
  }
#undef ITER
#undef LOADAB

  // h2 tile: tanh -> h2L[32][256] (512B rows), swizzled 16B slots
#pragma unroll
  for (int n = 0; n < 4; ++n) {
    int cb = wn * 64 + n * 16 + lk4 * 4;     // 4 consecutive cols
    float c0 = b2l[cb], c1 = b2l[cb + 1], c2 = b2l[cb + 2], c3 = b2l[cb + 3];
    int o = cb >> 3, half = (cb >> 2) & 1;
#pragma unroll
    for (int m = 0; m < 2; ++m) {
      int smp = m * 16 + lrow;
      u64 pk = pack4(ftanh(acc[n][m][0] + c0), ftanh(acc[n][m][1] + c1),
                     ftanh(acc[n][m][2] + c2), ftanh(acc[n][m][3] + c3));
      int sl = (o & 24) | ((o & 7) ^ (smp & 7));
      *(u64*)((char*)h2L + smp * 512 + (sl << 4) + half * 8) = pk;
    }
  }
  __syncthreads();

  // L3 partial: D[kcol][sample]; wave = 32 kcols x 16 samples, K=256
  {
    const int st = wid >> 1, ktp = wid & 1;
    const int smp = st * 16 + lrow;
    const char* Ar = (const char*)h2L + smp * 512;
    const int sx = smp & 7;
    f32x4 a3[2] = {};
#pragma unroll
    for (int ks = 0; ks < 8; ++ks) {
      int slu = ks * 4 + lk4;
      bf16x8 hf = *(const bf16x8*)(Ar + (((slu & 24) | ((slu & 7) ^ sx)) << 4));
#pragma unroll
      for (int n = 0; n < 2; ++n) {
        int fid = (ktp * 2 + n) * 32 + blockIdx.y * 8 + ks;
        bf16x8 pw = *(const bf16x8*)(P3 + ((size_t)fid << 9) + lane * 8);
        a3[n] = __builtin_amdgcn_mfma_f32_16x16x32_bf16(pw, hf, a3[n], 0, 0, 0);
      }
    }
    float* kp = kpart + (size_t)blockIdx.y * SN;
#pragma unroll
    for (int n = 0; n < 2; ++n)
      *(f32x4*)(kp + (size_t)(brow + smp) * 64 + (ktp * 2 + n) * 16 + lk4 * 4) = a3[n];
  }
}

// ---------------- final output: out = theta0 + (K1 + 4*K2 + k3)/6 ---------
__global__ __launch_bounds__(256) void k_out(
    const float* __restrict__ theta0, const float* __restrict__ K1,
    const float* __restrict__ K2, const float* __restrict__ kpart,
    const float* __restrict__ b3, float* __restrict__ out) {
  int gi = (blockIdx.x * 256 + threadIdx.x) * 4;
  f32x4 kv = *(const f32x4*)(kpart + gi);
  f32x4 p1 = *(const f32x4*)(kpart + SN + gi);
  f32x4 p2 = *(const f32x4*)(kpart + 2 * SN + gi);
  f32x4 p3 = *(const f32x4*)(kpart + 3 * SN + gi);
  f32x4 bv = *(const f32x4*)(b3 + (gi & 63));
  f32x4 k1 = *(const f32x4*)(K1 + gi);
  f32x4 k2 = *(const f32x4*)(K2 + gi);
  f32x4 t  = *(const f32x4*)(theta0 + gi);
#pragma unroll
  for (int j = 0; j < 4; ++j) {
    float k3 = kv[j] + p1[j] + p2[j] + p3[j] + bv[j];
    t[j] += (k1[j] + 4.f * k2[j] + k3) * (1.f / 6.f);
  }
  *(f32x4*)(out + gi) = t;
}

// ---------------- host ----------------

extern "C" void kernel_launch(void* const* d_in, const int* in_sizes, int n_in,
                              void* d_out, int out_size, void* d_ws, size_t ws_size,
                              hipStream_t stream) {
  const float* theta0 = (const float*)d_in[0];
  const float* ctx    = (const float*)d_in[1];
  const float* W1     = (const float*)d_in[2];
  const float* b1     = (const float*)d_in[3];
  const float* W2     = (const float*)d_in[4];
  const float* b2     = (const float*)d_in[5];
  const float* W3     = (const float*)d_in[6];
  const float* b3     = (const float*)d_in[7];
  const float* w1t    = W1 + (size_t)64 * 1024;   // time row of W1

  char* ws = (char*)d_ws;
  size_t o = 0;
  float* K1    = (float*)(ws + o); o += (size_t)SN * 4;            // 2 MB
  float* K2    = (float*)(ws + o); o += (size_t)SN * 4;            // 2 MB
  float* base1 = (float*)(ws + o); o += 4096;
  u16* P2  = (u16*)(ws + o); o += (size_t)1024 * 1024 * 2;         // 2 MB
  u16* P1  = (u16*)(ws + o); o += (size_t)64 * 1024 * 2;           // 128 KB
  u16* P3  = (u16*)(ws + o); o += (size_t)1024 * 64 * 2;           // 128 KB
  float* kpart = (float*)(ws + o); o += (size_t)4 * SN * 4;        // 8 MB
  u16* h1P = (u16*)(ws + o); o += (size_t)8192 * 1024 * 2;         // 16 MB

  k_prep<<<dim3(580), 256, 0, stream>>>(W1, b1, ctx, base1, W2, W3, P1, P2, P3);

  // One Kutta RK3 step, h = 1: stage times 0, 0.5, 1.0
  const float ts[3] = {0.f, 0.5f, 1.f};
  for (int s = 0; s < 3; ++s) {
    k_l1<<<dim3(256), 512, 0, stream>>>(theta0, kpart, b3, K1, K2, base1,
                                        w1t, P1, h1P, ts[s], s);
    k_fwd<<<dim3(256, 4), 256, 0, stream>>>(h1P, P2, b2, P3, kpart);
  }
  k_out<<<dim3(512), 256, 0, stream>>>(theta0, K1, K2, kpart, b3, (float*)d_out);
}

// Round 20
// 151.258 us; speedup vs baseline: 1.1475x; 1.1475x over previous
//
#include <hip/hip_runtime.h>

#define SN (8192 * 64)

typedef unsigned short u16;
typedef unsigned int   u32;
typedef unsigned long long u64;
typedef __bf16 bf16x8 __attribute__((ext_vector_type(8)));
typedef float  f32x4  __attribute__((ext_vector_type(4)));

__device__ __forceinline__ u16 bfc(float x) {
  union { __bf16 b; u16 u; } v; v.b = (__bf16)x; return v.u;
}
__device__ __forceinline__ u64 pack4(float a, float b, float c, float d) {
  return (u64)bfc(a) | ((u64)bfc(b) << 16) | ((u64)bfc(c) << 32) | ((u64)bfc(d) << 48);
}
__device__ __forceinline__ float ftanh(float x) {
  float e = __expf(2.f * x);
  return 1.f - 2.f / (e + 1.f);
}

// ---------------- merged prep kernel ----------------
__device__ __forceinline__ void pack_body(
    const float* __restrict__ W, u16* __restrict__ P, int ksl, int N, int gid) {
  int lane = gid & 63, fid = gid >> 6;
  int ks = fid & ((1 << ksl) - 1);
  int nt = fid >> ksl;
  int n  = nt * 16 + (lane & 15);
  int k0 = ks * 32 + (lane >> 4) * 8;
  u64 lo = pack4(W[(size_t)k0 * N + n], W[(size_t)(k0 + 1) * N + n],
                 W[(size_t)(k0 + 2) * N + n], W[(size_t)(k0 + 3) * N + n]);
  u64 hi = pack4(W[(size_t)(k0 + 4) * N + n], W[(size_t)(k0 + 5) * N + n],
                 W[(size_t)(k0 + 6) * N + n], W[(size_t)(k0 + 7) * N + n]);
  u64* dst = (u64*)(P + (size_t)gid * 8);
  dst[0] = lo; dst[1] = hi;
}

// grid 580: [0,512) P2 ; [512,544) P1 ; [544,576) P3 ; [576,580) base1
__global__ __launch_bounds__(256) void k_prep(
    const float* __restrict__ W1, const float* __restrict__ b1,
    const float* __restrict__ ctx, float* __restrict__ base1,
    const float* __restrict__ W2, const float* __restrict__ W3,
    u16* __restrict__ P1, u16* __restrict__ P2, u16* __restrict__ P3) {
  int bid = blockIdx.x, tid = threadIdx.x;
  if (bid < 512) {
    pack_body(W2, P2, 5, 1024, bid * 256 + tid);
  } else if (bid < 544) {
    pack_body(W1, P1, 1, 1024, (bid - 512) * 256 + tid);
  } else if (bid < 576) {
    pack_body(W3, P3, 5, 64, (bid - 544) * 256 + tid);
  } else {
    int j = (bid - 576) * 256 + tid;
    float s = b1[j];
    for (int c = 0; c < 256; ++c)
      s += ctx[c] * W1[(size_t)(65 + c) * 1024 + j];
    base1[j] = s;
  }
}

// ---------------- k_l1: RK3-stage update + layer1 -> h1P ----------------
// Single Kutta RK3 step, h=1:
//   mode 0: x = theta0
//   mode 1: k1 = sum(kpart)+b3 ; K1 = k1 ; x = theta0 + 0.5*k1
//   mode 2: k2 = sum(kpart)+b3 ; K2 = k2 ; x = theta0 - K1 + 2*k2
__global__ __launch_bounds__(512, 4) void k_l1(
    const float* __restrict__ theta0, const float* __restrict__ kpart,
    const float* __restrict__ b3, float* __restrict__ K1,
    float* __restrict__ K2, const float* __restrict__ base1,
    const float* __restrict__ w1t, const u16* __restrict__ P1,
    u16* __restrict__ h1P, float t_s, int mode) {
  __shared__ u16 xs[32 * 64];          // 4 KB, 128B rows, slot ^= row&7
  __shared__ float bias[1024];         // 4 KB
  const int tid = threadIdx.x, wid = tid >> 6, lane = tid & 63;
  const int lrow = lane & 15, lk4 = lane >> 4;
  const int brow = blockIdx.x * 32;

  bias[tid]       = base1[tid]       + t_s * w1t[tid];
  bias[tid + 512] = base1[tid + 512] + t_s * w1t[tid + 512];

  {
    int row = tid >> 4, d = (tid & 15) * 4;
    int gi = (brow + row) * 64 + d;
    f32x4 x;
    if (mode == 0) {
      x = *(const f32x4*)(theta0 + gi);
    } else {
      f32x4 kv = *(const f32x4*)(kpart + gi);
      f32x4 p1 = *(const f32x4*)(kpart + SN + gi);
      f32x4 p2 = *(const f32x4*)(kpart + 2 * SN + gi);
      f32x4 p3 = *(const f32x4*)(kpart + 3 * SN + gi);
      f32x4 bv = *(const f32x4*)(b3 + d);
      f32x4 t0 = *(const f32x4*)(theta0 + gi);
#pragma unroll
      for (int j = 0; j < 4; ++j) kv[j] += p1[j] + p2[j] + p3[j] + bv[j];
      if (mode == 1) {
        *(f32x4*)(K1 + gi) = kv;
#pragma unroll
        for (int j = 0; j < 4; ++j) x[j] = t0[j] + 0.5f * kv[j];
      } else {
        f32x4 k1v = *(const f32x4*)(K1 + gi);
        *(f32x4*)(K2 + gi) = kv;
#pragma unroll
        for (int j = 0; j < 4; ++j) x[j] = t0[j] - k1v[j] + 2.f * kv[j];
      }
    }
    int slot = d >> 3, half = (d >> 2) & 1;
    *(u64*)((char*)xs + row * 128 + ((slot ^ (row & 7)) << 4) + half * 8)
        = pack4(x[0], x[1], x[2], x[3]);
  }
  __syncthreads();

#pragma unroll 1
  for (int nt = 0; nt < 8; ++nt) {
    const int n0 = wid * 128 + nt * 16;
    f32x4 acc[2] = {{0.f,0.f,0.f,0.f},{0.f,0.f,0.f,0.f}};
#pragma unroll
    for (int ks = 0; ks < 2; ++ks) {
      bf16x8 pw = *(const bf16x8*)(P1 + ((size_t)((n0 >> 4) * 2 + ks) << 9) + lane * 8);
#pragma unroll
      for (int st = 0; st < 2; ++st) {
        int row = st * 16 + lrow;
        bf16x8 xa = *(const bf16x8*)((char*)xs + row * 128 +
                                     (((ks * 4 + lk4) ^ (row & 7)) << 4));
        acc[st] = __builtin_amdgcn_mfma_f32_16x16x32_bf16(pw, xa, acc[st], 0, 0, 0);
      }
    }
    float bb0 = bias[n0 + lk4 * 4], bb1 = bias[n0 + lk4 * 4 + 1];
    float bb2 = bias[n0 + lk4 * 4 + 2], bb3 = bias[n0 + lk4 * 4 + 3];
    const int ks2 = n0 >> 5;
    const int lane2 = lrow + 16 * ((nt & 1) * 2 + (lk4 >> 1));
    const size_t off = (size_t)lane2 * 8 + (lk4 & 1) * 4;   // u16 units
#pragma unroll
    for (int st = 0; st < 2; ++st) {
      u64 pk = pack4(ftanh(acc[st][0] + bb0), ftanh(acc[st][1] + bb1),
                     ftanh(acc[st][2] + bb2), ftanh(acc[st][3] + bb3));
      *(u64*)(h1P + ((((size_t)(brow >> 4) + st) * 32 + ks2) << 9) + off) = pk;
    }
  }
}

// ---------------- k_fwd: layer2 + tanh + layer3-partial ----------------
// Tile 32 samples x 256 cols (grid 256 x 4), 256 thr = 4 waves.
// __launch_bounds__(256,3): 3 blocks/CU measured optimal (4/CU thrashes
// the per-CU delivery path: round 19 regressed 152->174 us; 2/CU = 396).
// BARRIER-FREE K-loop, register-streamed A/B, setprio around MFMA (T5).
__global__ __launch_bounds__(256, 3) void k_fwd(
    const u16* __restrict__ h1P, const u16* __restrict__ P2,
    const float* __restrict__ b2, const u16* __restrict__ P3,
    float* __restrict__ kpart) {
  __shared__ u16 h2L[32 * 256];      // 16 KB
  __shared__ float b2l[256];         // 1 KB
  const int tid = threadIdx.x, wid = tid >> 6, lane = tid & 63;
  const int lrow = lane & 15, lk4 = lane >> 4;
  const int brow = blockIdx.x * 32, bcol = blockIdx.y * 256;
  const int wn = wid;                 // wave col-block (4 x 64 cols)

  b2l[tid] = b2[bcol + tid];
  __syncthreads();                    // b2l visible (only barrier pre-loop)

  const u16* Ph = h1P + (((size_t)(brow >> 4) * 32) << 9) + lane * 8;
  const u16* Pw = P2 + (((size_t)((bcol >> 4) + wn * 4) * 32) << 9) + lane * 8;

  bf16x8 AfE[2][2], AfO[2][2], BfE[2][4], BfO[2][4];
#define LOADAB(A, B, ks)                                                      \
  {                                                                           \
    _Pragma("unroll")                                                         \
    for (int n = 0; n < 4; ++n) {                                             \
      B[0][n] = *(const bf16x8*)(Pw + (((size_t)(n * 32 + (ks))) << 9));      \
      B[1][n] = *(const bf16x8*)(Pw + (((size_t)(n * 32 + (ks) + 1)) << 9));  \
    }                                                                         \
    _Pragma("unroll")                                                         \
    for (int m = 0; m < 2; ++m) {                                             \
      A[0][m] = *(const bf16x8*)(Ph + (((size_t)(m * 32 + (ks))) << 9));      \
      A[1][m] = *(const bf16x8*)(Ph + (((size_t)(m * 32 + (ks) + 1)) << 9));  \
    }                                                                         \
  }

  LOADAB(AfE, BfE, 0);

  f32x4 acc[4][2] = {};

#define ITER(T, AC, BC, AN, BN)                                               \
  {                                                                           \
    if ((T) < 15) LOADAB(AN, BN, 2 * (T) + 2);                                \
    __builtin_amdgcn_s_setprio(1);                                            \
    _Pragma("unroll")                                                         \
    for (int n = 0; n < 4; ++n)                                               \
      _Pragma("unroll")                                                       \
      for (int m = 0; m < 2; ++m)                                             \
        acc[n][m] = __builtin_amdgcn_mfma_f32_16x16x32_bf16(BC[0][n], AC[0][m],\
                                                            acc[n][m], 0, 0, 0);\
    _Pragma("unroll")                                                         \
    for (int n = 0; n < 4; ++n)                                               \
      _Pragma("unroll")                                                       \
      for (int m = 0; m < 2; ++m)                                             \
        acc[n][m] = __builtin_amdgcn_mfma_f32_16x16x32_bf16(BC[1][n], AC[1][m],\
                                                            acc[n][m], 0, 0, 0);\
    __builtin_amdgcn_s_setprio(0);                                            \
  }

#pragma unroll 1
  for (int tt = 0; tt < 8; ++tt) {
    ITER(2 * tt,     AfE, BfE, AfO, BfO);
    ITER(2 * tt + 1, AfO, BfO, AfE, BfE);
  }
#undef ITER
#undef LOADAB

  // h2 tile: tanh -> h2L[32][256] (512B rows), swizzled 16B slots
#pragma unroll
  for (int n = 0; n < 4; ++n) {
    int cb = wn * 64 + n * 16 + lk4 * 4;     // 4 consecutive cols
    float c0 = b2l[cb], c1 = b2l[cb + 1], c2 = b2l[cb + 2], c3 = b2l[cb + 3];
    int o = cb >> 3, half = (cb >> 2) & 1;
#pragma unroll
    for (int m = 0; m < 2; ++m) {
      int smp = m * 16 + lrow;
      u64 pk = pack4(ftanh(acc[n][m][0] + c0), ftanh(acc[n][m][1] + c1),
                     ftanh(acc[n][m][2] + c2), ftanh(acc[n][m][3] + c3));
      int sl = (o & 24) | ((o & 7) ^ (smp & 7));
      *(u64*)((char*)h2L + smp * 512 + (sl << 4) + half * 8) = pk;
    }
  }
  __syncthreads();

  // L3 partial: D[kcol][sample]; wave = 32 kcols x 16 samples, K=256
  {
    const int st = wid >> 1, ktp = wid & 1;
    const int smp = st * 16 + lrow;
    const char* Ar = (const char*)h2L + smp * 512;
    const int sx = smp & 7;
    f32x4 a3[2] = {};
#pragma unroll
    for (int ks = 0; ks < 8; ++ks) {
      int slu = ks * 4 + lk4;
      bf16x8 hf = *(const bf16x8*)(Ar + (((slu & 24) | ((slu & 7) ^ sx)) << 4));
#pragma unroll
      for (int n = 0; n < 2; ++n) {
        int fid = (ktp * 2 + n) * 32 + blockIdx.y * 8 + ks;
        bf16x8 pw = *(const bf16x8*)(P3 + ((size_t)fid << 9) + lane * 8);
        a3[n] = __builtin_amdgcn_mfma_f32_16x16x32_bf16(pw, hf, a3[n], 0, 0, 0);
      }
    }
    float* kp = kpart + (size_t)blockIdx.y * SN;
#pragma unroll
    for (int n = 0; n < 2; ++n)
      *(f32x4*)(kp + (size_t)(brow + smp) * 64 + (ktp * 2 + n) * 16 + lk4 * 4) = a3[n];
  }
}

// ---------------- final output: out = theta0 + (K1 + 4*K2 + k3)/6 ---------
__global__ __launch_bounds__(256) void k_out(
    const float* __restrict__ theta0, const float* __restrict__ K1,
    const float* __restrict__ K2, const float* __restrict__ kpart,
    const float* __restrict__ b3, float* __restrict__ out) {
  int gi = (blockIdx.x * 256 + threadIdx.x) * 4;
  f32x4 kv = *(const f32x4*)(kpart + gi);
  f32x4 p1 = *(const f32x4*)(kpart + SN + gi);
  f32x4 p2 = *(const f32x4*)(kpart + 2 * SN + gi);
  f32x4 p3 = *(const f32x4*)(kpart + 3 * SN + gi);
  f32x4 bv = *(const f32x4*)(b3 + (gi & 63));
  f32x4 k1 = *(const f32x4*)(K1 + gi);
  f32x4 k2 = *(const f32x4*)(K2 + gi);
  f32x4 t  = *(const f32x4*)(theta0 + gi);
#pragma unroll
  for (int j = 0; j < 4; ++j) {
    float k3 = kv[j] + p1[j] + p2[j] + p3[j] + bv[j];
    t[j] += (k1[j] + 4.f * k2[j] + k3) * (1.f / 6.f);
  }
  *(f32x4*)(out + gi) = t;
}

// ---------------- host ----------------

extern "C" void kernel_launch(void* const* d_in, const int* in_sizes, int n_in,
                              void* d_out, int out_size, void* d_ws, size_t ws_size,
                              hipStream_t stream) {
  const float* theta0 = (const float*)d_in[0];
  const float* ctx    = (const float*)d_in[1];
  const float* W1     = (const float*)d_in[2];
  const float* b1     = (const float*)d_in[3];
  const float* W2     = (const float*)d_in[4];
  const float* b2     = (const float*)d_in[5];
  const float* W3     = (const float*)d_in[6];
  const float* b3     = (const float*)d_in[7];
  const float* w1t    = W1 + (size_t)64 * 1024;   // time row of W1

  char* ws = (char*)d_ws;
  size_t o = 0;
  float* K1    = (float*)(ws + o); o += (size_t)SN * 4;            // 2 MB
  float* K2    = (float*)(ws + o); o += (size_t)SN * 4;            // 2 MB
  float* base1 = (float*)(ws + o); o += 4096;
  u16* P2  = (u16*)(ws + o); o += (size_t)1024 * 1024 * 2;         // 2 MB
  u16* P1  = (u16*)(ws + o); o += (size_t)64 * 1024 * 2;           // 128 KB
  u16* P3  = (u16*)(ws + o); o += (size_t)1024 * 64 * 2;           // 128 KB
  float* kpart = (float*)(ws + o); o += (size_t)4 * SN * 4;        // 8 MB
  u16* h1P = (u16*)(ws + o); o += (size_t)8192 * 1024 * 2;         // 16 MB

  k_prep<<<dim3(580), 256, 0, stream>>>(W1, b1, ctx, base1, W2, W3, P1, P2, P3);

  // One Kutta RK3 step, h = 1: stage times 0, 0.5, 1.0
  const float ts[3] = {0.f, 0.5f, 1.f};
  for (int s = 0; s < 3; ++s) {
    k_l1<<<dim3(256), 512, 0, stream>>>(theta0, kpart, b3, K1, K2, base1,
                                        w1t, P1, h1P, ts[s], s);
    k_fwd<<<dim3(256, 4), 256, 0, stream>>>(h1P, P2, b2, P3, kpart);
  }
  k_out<<<dim3(512), 256, 0, stream>>>(theta0, K1, K2, kpart, b3, (float*)d_out);
}